// Round 6
// baseline (171.950 us; speedup 1.0000x reference)
//
#include <hip/hip_runtime.h>
#include <cstdint>

#define NB   32
#define CIN  128
#define HH   56
#define WW   56
#define KOUT 256
#define HWS  (HH*WW)            // 3136
#define NHW  (NB*HWS)           // 100352
#define PADH 58                 // rows -1..56 -> 0..57 (0 and 57 zero pad)
#define XCNT ((float)(NB*CIN*HWS))
#define WCNT ((float)(KOUT*CIN*9))

typedef uint32_t u32x4 __attribute__((ext_vector_type(4)));

// Zero sums + zero the 2 pad rows per image (3584 uint4). Grid 14 x 256.
__global__ __launch_bounds__(256) void init_kernel(uint4* __restrict__ xpad,
                                                   float* __restrict__ sums) {
    int idx = blockIdx.x * 256 + threadIdx.x;        // 0..3583
    if (idx < 2) sums[idx] = 0.0f;
    int n = idx / 112, rem = idx - n * 112;
    int prow = (rem < 56) ? 0 : 57;
    int w = rem % 56;
    xpad[(n * PADH + prow) * WW + w] = make_uint4(0, 0, 0, 0);
}

__device__ __forceinline__ void block_reduce_add(float v, float* dst) {
    #pragma unroll
    for (int off = 32; off > 0; off >>= 1) v += __shfl_down(v, off);
    __shared__ float ws4[4];
    int lane = threadIdx.x & 63, wid = threadIdx.x >> 6;
    if (lane == 0) ws4[wid] = v;
    __syncthreads();
    if (threadIdx.x == 0) {
        float s = ws4[0];
        int nw = (blockDim.x + 63) >> 6;
        for (int i = 1; i < nw; i++) s += ws4[i];
        atomicAdd(dst, s);
    }
}

// Thread per (spatial idx, 32-channel word j); writes into PADDED layout.
__global__ __launch_bounds__(256) void pack_x_kernel(const float* __restrict__ x,
                                                     uint32_t* __restrict__ xpadw,
                                                     float* __restrict__ sums) {
    int j   = blockIdx.x / (NHW / 256);              // 0..3, uniform per block
    int idx = (blockIdx.x - j * (NHW / 256)) * 256 + threadIdx.x;
    int n  = idx / HWS;
    int hw = idx - n * HWS;
    int h  = hw / WW;
    int w  = hw - h * WW;
    const float* p = x + (size_t)n * CIN * HWS + (size_t)(j * 32) * HWS + hw;
    float asum = 0.0f;
    uint32_t bits = 0;
    #pragma unroll
    for (int t = 0; t < 32; t++) {
        float v = p[(size_t)t * HWS];
        asum += fabsf(v);
        bits |= (v > 0.0f ? 1u : 0u) << t;
    }
    xpadw[(((n * PADH + h + 1) * WW + w) << 2) + j] = bits;
    block_reduce_add(asum, &sums[0]);
}

// Thread per (k, tap, word j): block = (tap, j) [36 blocks], lane = k (256).
__global__ __launch_bounds__(256) void pack_w_kernel(const float* __restrict__ wgt,
                                                     uint32_t* __restrict__ wpackTw,
                                                     float* __restrict__ sums) {
    int k   = threadIdx.x;
    int tap = blockIdx.x >> 2;
    int j   = blockIdx.x & 3;
    const float* p = wgt + (size_t)k * CIN * 9 + (size_t)(j * 32) * 9 + tap;
    float asum = 0.0f;
    uint32_t bits = 0;
    #pragma unroll
    for (int t = 0; t < 32; t++) {
        float v = p[(size_t)t * 9];
        asum += fabsf(v);
        bits |= (v > 0.0f ? 1u : 0u) << t;
    }
    wpackTw[(tap * KOUT + k) * 4 + j] = bits;
    block_reduce_add(asum, &sums[1]);
}

// Block = (n,h), 4 independent waves (wave = kgroup), lane = k in group.
// No barriers. x columns: asm-volatile global_load_dwordx4 into a 4-slot
// register rotation (prefetch distance 2 bodies); consume points start with
// s_waitcnt vmcnt(3) whose "+v" ties make the popcounts data-dependent on it
// (compiler cannot sink the loads or hoist the uses). Pad rows are real zero
// rows in xpad; pad columns are algebraic (cs0/cs2 folded into F0/F55).
__global__ __launch_bounds__(256, 4) void conv_kernel(const u32x4* __restrict__ xpad,
                                                      const uint4* __restrict__ wpackT,
                                                      const float* __restrict__ sums,
                                                      const float* __restrict__ bias,
                                                      float* __restrict__ out) {
    __shared__ float sbuf[256 * 10];

    int tid = threadIdx.x;
    int l   = tid & 63, wid = tid >> 6;     // wid = kgroup
    int bid = blockIdx.x;
    int n   = bid / HH, h = bid - n * HH;

    u32x4 wq[9];
    #pragma unroll
    for (int t = 0; t < 9; t++) {
        uint4 q = wpackT[t * KOUT + tid];
        wq[t] = (u32x4){q.x, q.y, q.z, q.w};
    }

    float scale = (sums[0] * (1.0f / XCNT)) * (sums[1] * (1.0f / WCNT));
    float m2s   = -2.0f * scale;
    float cbase = 1152.0f * scale + bias[tid];

    int pw[9];
    #pragma unroll
    for (int t = 0; t < 9; t++)
        pw[t] = __popc(wq[t][0]) + __popc(wq[t][1]) + __popc(wq[t][2]) + __popc(wq[t][3]);
    int cs0 = pw[0] + pw[3] + pw[6];
    int cs2 = pw[2] + pw[5] + pw[8];
    int rterm = 0, cc0 = 0, cc2 = 0;
    if (h == 0)        { rterm = 2*(pw[0]+pw[1]+pw[2]) - 384; cc0 = 128 - 2*pw[0]; cc2 = 128 - 2*pw[2]; }
    else if (h == HH-1){ rterm = 2*(pw[6]+pw[7]+pw[8]) - 384; cc0 = 128 - 2*pw[6]; cc2 = 128 - 2*pw[8]; }
    float CB  = cbase + scale * (float)rterm;
    float F0  = CB + scale * (float)(2*cs0 - 384 + cc0);
    float F55 = CB + scale * (float)(2*cs2 - 384 + cc2);

    // 3-row window base pointers (padded rows h, h+1, h+2)
    const u32x4* R0 = xpad + (size_t)(n * PADH + h) * WW;
    const u32x4* R1 = R0 + WW;
    const u32x4* R2 = R1 + WW;

    float* sb   = &sbuf[tid * 10];
    int    fbase = (wid * 64 + (l >> 2)) * 10 + (l & 3) * 2;
    float* o0   = out + ((size_t)(n * KOUT + wid * 64 + (l >> 2)) * HWS + h * WW + (l & 3) * 2);

    u32x4 xs[4][3];   // slot s holds column c with c % 4 == s

#define GLD(dst, base, OFF) asm volatile("global_load_dwordx4 %0, %1, off offset:" OFF \
                                         : "=v"(dst) : "v"(base));
#define PF(S, OFF) { GLD(xs[S][0], R0, OFF) GLD(xs[S][1], R1, OFF) GLD(xs[S][2], R2, OFF) }
#define WAITV(S, CNT) asm volatile("s_waitcnt vmcnt(" CNT ")" \
                                   : "+v"(xs[S][0]), "+v"(xs[S][1]), "+v"(xs[S][2]));
#define T4(a, q, wt) { u32x4 t_ = (q) ^ (wt); \
    a += __popc(t_[0]) + __popc(t_[1]) + __popc(t_[2]) + __popc(t_[3]); }
#define CORE(J) \
    int a0 = 0, a1 = 0, a2 = 0; \
    T4(a0, xs[(J)&3][0], wq[0]) T4(a0, xs[((J)+1)&3][0], wq[1]) T4(a0, xs[((J)+2)&3][0], wq[2]) \
    T4(a1, xs[(J)&3][1], wq[3]) T4(a1, xs[((J)+1)&3][1], wq[4]) T4(a1, xs[((J)+2)&3][1], wq[5]) \
    T4(a2, xs[(J)&3][2], wq[6]) T4(a2, xs[((J)+1)&3][2], wq[7]) T4(a2, xs[((J)+2)&3][2], wq[8])
#define BODY(J, OFF)    { WAITV(((J)+2)&3, "3") CORE(J) PF((J)&3, OFF) \
                          sb[((J)+1)&7] = fmaf(m2s, (float)(a0+a1+a2), CB); }
#define BODYNP(J, CNT)  { WAITV(((J)+2)&3, CNT) CORE(J) \
                          sb[((J)+1)&7] = fmaf(m2s, (float)(a0+a1+a2), CB); }
#define FLUSH { \
    *(float2*)(o0)            = *(float2*)&sbuf[fbase]; \
    *(float2*)(o0 + 16*HWS)   = *(float2*)&sbuf[fbase + 160]; \
    *(float2*)(o0 + 32*HWS)   = *(float2*)&sbuf[fbase + 320]; \
    *(float2*)(o0 + 48*HWS)   = *(float2*)&sbuf[fbase + 480]; \
    o0 += 8; }

    // prologue: issue cols 0..3
    PF(0, "0") PF(1, "16") PF(2, "32") PF(3, "48")
    asm volatile("s_waitcnt vmcnt(6)"
                 : "+v"(xs[0][0]), "+v"(xs[0][1]), "+v"(xs[0][2]),
                   "+v"(xs[1][0]), "+v"(xs[1][1]), "+v"(xs[1][2]));

    // w = 0 edge: pad col (cs0) + cols 0,1
    {
        int a0 = cs0, a1 = 0, a2 = 0;
        T4(a0, xs[0][0], wq[1]) T4(a0, xs[1][0], wq[2])
        T4(a1, xs[0][1], wq[4]) T4(a1, xs[1][1], wq[5])
        T4(a2, xs[0][2], wq[7]) T4(a2, xs[1][2], wq[8])
        sb[0] = fmaf(m2s, (float)(a0 + a1 + a2), F0);
    }

    // interior w = 1..48: 6 groups x 8 bodies; R* base = column 8i
    #pragma unroll 1
    for (int i = 0; i < 6; i++) {
        BODY(0, "64")  BODY(1, "80")  BODY(2, "96")  BODY(3, "112")
        BODY(4, "128") BODY(5, "144") BODY(6, "160")
        FLUSH
        BODY(7, "176")
        R0 += 8; R1 += 8; R2 += 8;
    }

    // tail w = 49..54 (base at col 48); prefetches cover cols 52..55 then stop
    BODY(0, "64") BODY(1, "80") BODY(2, "96") BODY(3, "112")
    BODYNP(4, "3") BODYNP(5, "0")

    // w = 55 edge: cols 54,55 + pad col (cs2)
    {
        int a0 = cs2, a1 = 0, a2 = 0;
        T4(a0, xs[2][0], wq[0]) T4(a0, xs[3][0], wq[1])
        T4(a1, xs[2][1], wq[3]) T4(a1, xs[3][1], wq[4])
        T4(a2, xs[2][2], wq[6]) T4(a2, xs[3][2], wq[7])
        sb[7] = fmaf(m2s, (float)(a0 + a1 + a2), F55);
        FLUSH
    }
}

extern "C" void kernel_launch(void* const* d_in, const int* in_sizes, int n_in,
                              void* d_out, int out_size, void* d_ws, size_t ws_size,
                              hipStream_t stream) {
    const float* x    = (const float*)d_in[0];
    const float* wgt  = (const float*)d_in[1];
    const float* bias = (const float*)d_in[2];
    float* out = (float*)d_out;

    // ws: sums (256B) | xpad 32*58*56 uint4 (1.59MB) | wpackT 2304 uint4 (36KB)
    float* sums   = (float*)d_ws;
    uint4* xpad   = (uint4*)((char*)d_ws + 256);
    uint4* wpackT = (uint4*)((char*)d_ws + 256 + (size_t)NB * PADH * WW * 16);

    hipLaunchKernelGGL(init_kernel, dim3(14), dim3(256), 0, stream, xpad, sums);
    hipLaunchKernelGGL(pack_w_kernel, dim3(36), dim3(256), 0, stream, wgt, (uint32_t*)wpackT, sums);
    hipLaunchKernelGGL(pack_x_kernel, dim3(4 * NHW / 256), dim3(256), 0, stream, x, (uint32_t*)xpad, sums);
    hipLaunchKernelGGL(conv_kernel, dim3(NB * HH), dim3(256), 0, stream,
                       (const u32x4*)xpad, wpackT, sums, bias, out);
}

// Round 7
// 137.448 us; speedup vs baseline: 1.2510x; 1.2510x over previous
//
#include <hip/hip_runtime.h>
#include <cstdint>

#define NB   32
#define CIN  128
#define HH   56
#define WW   56
#define KOUT 256
#define HWS  (HH*WW)            // 3136
#define NHW  (NB*HWS)           // 100352
#define PADH 58                 // rows -1..56 -> 0..57 (0 and 57 zero pad)
#define XCNT ((float)(NB*CIN*HWS))
#define WCNT ((float)(KOUT*CIN*9))

// Zero sums + zero the 2 pad rows per image (3584 uint4). Grid 14 x 256.
__global__ __launch_bounds__(256) void init_kernel(uint4* __restrict__ xpad,
                                                   float* __restrict__ sums) {
    int idx = blockIdx.x * 256 + threadIdx.x;        // 0..3583
    if (idx < 2) sums[idx] = 0.0f;
    int n = idx / 112, rem = idx - n * 112;
    int prow = (rem < 56) ? 0 : 57;
    int w = rem % 56;
    xpad[(n * PADH + prow) * WW + w] = make_uint4(0, 0, 0, 0);
}

__device__ __forceinline__ void block_reduce_add(float v, float* dst) {
    #pragma unroll
    for (int off = 32; off > 0; off >>= 1) v += __shfl_down(v, off);
    __shared__ float ws4[4];
    int lane = threadIdx.x & 63, wid = threadIdx.x >> 6;
    if (lane == 0) ws4[wid] = v;
    __syncthreads();
    if (threadIdx.x == 0) {
        float s = ws4[0];
        int nw = (blockDim.x + 63) >> 6;
        for (int i = 1; i < nw; i++) s += ws4[i];
        atomicAdd(dst, s);
    }
}

// Thread per (spatial idx, 32-channel word j); writes into PADDED layout.
__global__ __launch_bounds__(256) void pack_x_kernel(const float* __restrict__ x,
                                                     uint32_t* __restrict__ xpadw,
                                                     float* __restrict__ sums) {
    int j   = blockIdx.x / (NHW / 256);              // 0..3, uniform per block
    int idx = (blockIdx.x - j * (NHW / 256)) * 256 + threadIdx.x;
    int n  = idx / HWS;
    int hw = idx - n * HWS;
    int h  = hw / WW;
    int w  = hw - h * WW;
    const float* p = x + (size_t)n * CIN * HWS + (size_t)(j * 32) * HWS + hw;
    float asum = 0.0f;
    uint32_t bits = 0;
    #pragma unroll
    for (int t = 0; t < 32; t++) {
        float v = p[(size_t)t * HWS];
        asum += fabsf(v);
        bits |= (v > 0.0f ? 1u : 0u) << t;
    }
    xpadw[(((n * PADH + h + 1) * WW + w) << 2) + j] = bits;
    block_reduce_add(asum, &sums[0]);
}

// Thread per (k, tap, word j): block = (tap, j) [36 blocks], lane = k (256).
__global__ __launch_bounds__(256) void pack_w_kernel(const float* __restrict__ wgt,
                                                     uint32_t* __restrict__ wpackTw,
                                                     float* __restrict__ sums) {
    int k   = threadIdx.x;
    int tap = blockIdx.x >> 2;
    int j   = blockIdx.x & 3;
    const float* p = wgt + (size_t)k * CIN * 9 + (size_t)(j * 32) * 9 + tap;
    float asum = 0.0f;
    uint32_t bits = 0;
    #pragma unroll
    for (int t = 0; t < 32; t++) {
        float v = p[(size_t)t * 9];
        asum += fabsf(v);
        bits |= (v > 0.0f ? 1u : 0u) << t;
    }
    wpackTw[(tap * KOUT + k) * 4 + j] = bits;
    block_reduce_add(asum, &sums[1]);
}

// Block = (n,h), 256 threads = 4 INDEPENDENT kg-waves (no barriers).
// lane = k within group. x columns read from global (padded rows = real zeros)
// into a 4-slot rotation; compiler may sink/reload (broadcast L1 hits — cheap).
// Occupancy is the lever: launch_bounds(256,8) caps VGPR at 64 -> 7 blocks/CU
// resident (grid 1792 = 7/CU uniform) = 28 waves/CU covering latency via TLP.
// Pad columns algebraic (cs0/cs2 folded into F0/F55).
__global__ __launch_bounds__(256, 8) void conv_kernel(const uint4* __restrict__ xpad,
                                                      const uint4* __restrict__ wpackT,
                                                      const float* __restrict__ sums,
                                                      const float* __restrict__ bias,
                                                      float* __restrict__ out) {
    __shared__ float sbuf[256 * 10];

    int tid = threadIdx.x;
    int l   = tid & 63, kg = tid >> 6;
    int bid = blockIdx.x;
    int n   = bid / HH, h = bid - n * HH;

    uint4 wq[9];
    #pragma unroll
    for (int t = 0; t < 9; t++) wq[t] = wpackT[t * KOUT + tid];

    // 3-row window base (padded rows h, h+1, h+2 = hy h-1,h,h+1)
    const uint4* P = xpad + (size_t)(n * PADH + h) * WW;

    uint4 xs[4][3];   // slot s holds column c with c % 4 == s
#define PF(S, OFF) { xs[S][0] = PB[OFF]; xs[S][1] = PB[56 + (OFF)]; xs[S][2] = PB[112 + (OFF)]; }
    {
        const uint4* PB = P;
        PF(0, 0) PF(1, 1) PF(2, 2) PF(3, 3)
    }

    float scale = (sums[0] * (1.0f / XCNT)) * (sums[1] * (1.0f / WCNT));
    float m2s   = -2.0f * scale;
    float cbase = 1152.0f * scale + bias[tid];

    int pw[9];
    #pragma unroll
    for (int t = 0; t < 9; t++)
        pw[t] = __popc(wq[t].x) + __popc(wq[t].y) + __popc(wq[t].z) + __popc(wq[t].w);
    int cs0 = pw[0] + pw[3] + pw[6];
    int cs2 = pw[2] + pw[5] + pw[8];
    int rterm = 0, cc0 = 0, cc2 = 0;
    if (h == 0)        { rterm = 2*(pw[0]+pw[1]+pw[2]) - 384; cc0 = 128 - 2*pw[0]; cc2 = 128 - 2*pw[2]; }
    else if (h == HH-1){ rterm = 2*(pw[6]+pw[7]+pw[8]) - 384; cc0 = 128 - 2*pw[6]; cc2 = 128 - 2*pw[8]; }
    float CB  = cbase + scale * (float)rterm;
    float F0  = CB + scale * (float)(2*cs0 - 384 + cc0);
    float F55 = CB + scale * (float)(2*cs2 - 384 + cc2);

    float* sb    = &sbuf[tid * 10];
    int    fbase = (kg * 64 + (l >> 2)) * 10 + (l & 3) * 2;
    float* o0 = out + ((size_t)(n * KOUT + kg * 64 + (l >> 2)) * HWS + h * WW + (l & 3) * 2);
    float* o1 = o0 + (size_t)16 * HWS;
    float* o2 = o1 + (size_t)16 * HWS;
    float* o3 = o2 + (size_t)16 * HWS;

#define T4(a, q, wt) a += __popc((q).x^(wt).x) + __popc((q).y^(wt).y) + __popc((q).z^(wt).z) + __popc((q).w^(wt).w);
#define FLUSH(C) { \
    *(float2*)(o0 + (C) * 8) = *(float2*)&sbuf[fbase];       \
    *(float2*)(o1 + (C) * 8) = *(float2*)&sbuf[fbase + 160]; \
    *(float2*)(o2 + (C) * 8) = *(float2*)&sbuf[fbase + 320]; \
    *(float2*)(o3 + (C) * 8) = *(float2*)&sbuf[fbase + 480]; \
}
#define CORE(J) \
    int a0 = 0, a1 = 0, a2 = 0; \
    T4(a0, xs[(J)&3][0], wq[0]) T4(a0, xs[((J)+1)&3][0], wq[1]) T4(a0, xs[((J)+2)&3][0], wq[2]) \
    T4(a1, xs[(J)&3][1], wq[3]) T4(a1, xs[((J)+1)&3][1], wq[4]) T4(a1, xs[((J)+2)&3][1], wq[5]) \
    T4(a2, xs[(J)&3][2], wq[6]) T4(a2, xs[((J)+1)&3][2], wq[7]) T4(a2, xs[((J)+2)&3][2], wq[8])
#define BODY(J)   { CORE(J) PF((J)&3, (J)+4) sb[((J)+1)&7] = fmaf(m2s, (float)(a0+a1+a2), CB); }
#define BODYNP(J) { CORE(J) sb[((J)+1)&7] = fmaf(m2s, (float)(a0+a1+a2), CB); }

    // w = 0 edge: pad col (cs0) + cols 0,1
    {
        int a0 = cs0, a1 = 0, a2 = 0;
        T4(a0, xs[0][0], wq[1]) T4(a0, xs[1][0], wq[2])
        T4(a1, xs[0][1], wq[4]) T4(a1, xs[1][1], wq[5])
        T4(a2, xs[0][2], wq[7]) T4(a2, xs[1][2], wq[8])
        sb[0] = fmaf(m2s, (float)(a0 + a1 + a2), F0);
    }

    // interior w = 1..48: 6 groups x 8 bodies; PB base = column 8i
    {
        const uint4* PB = P;
        #pragma unroll 1
        for (int i = 0; i < 6; i++) {
            BODY(0) BODY(1) BODY(2) BODY(3) BODY(4) BODY(5)
            BODY(6)
            FLUSH(i)
            BODY(7)
            PB += 8;
        }
        // tail w = 49..54 (PB at col 48); prefetches cover cols 52..55 then stop
        BODY(0) BODY(1) BODY(2) BODY(3) BODYNP(4) BODYNP(5)
    }

    // w = 55 edge: cols 54,55 + pad col (cs2)
    {
        int a0 = cs2, a1 = 0, a2 = 0;
        T4(a0, xs[2][0], wq[0]) T4(a0, xs[3][0], wq[1])
        T4(a1, xs[2][1], wq[3]) T4(a1, xs[3][1], wq[4])
        T4(a2, xs[2][2], wq[6]) T4(a2, xs[3][2], wq[7])
        sb[7] = fmaf(m2s, (float)(a0 + a1 + a2), F55);
        FLUSH(6)
    }
}

extern "C" void kernel_launch(void* const* d_in, const int* in_sizes, int n_in,
                              void* d_out, int out_size, void* d_ws, size_t ws_size,
                              hipStream_t stream) {
    const float* x    = (const float*)d_in[0];
    const float* wgt  = (const float*)d_in[1];
    const float* bias = (const float*)d_in[2];
    float* out = (float*)d_out;

    // ws: sums (256B) | xpad 32*58*56 uint4 (1.59MB) | wpackT 2304 uint4 (36KB)
    float* sums   = (float*)d_ws;
    uint4* xpad   = (uint4*)((char*)d_ws + 256);
    uint4* wpackT = (uint4*)((char*)d_ws + 256 + (size_t)NB * PADH * WW * 16);

    hipLaunchKernelGGL(init_kernel, dim3(14), dim3(256), 0, stream, xpad, sums);
    hipLaunchKernelGGL(pack_w_kernel, dim3(36), dim3(256), 0, stream, wgt, (uint32_t*)wpackT, sums);
    hipLaunchKernelGGL(pack_x_kernel, dim3(4 * NHW / 256), dim3(256), 0, stream, x, (uint32_t*)xpad, sums);
    hipLaunchKernelGGL(conv_kernel, dim3(NB * HH), dim3(256), 0, stream, xpad, wpackT, sums, bias, out);
}

// Round 8
// 112.410 us; speedup vs baseline: 1.5297x; 1.2227x over previous
//
#include <hip/hip_runtime.h>
#include <cstdint>

#define NB   32
#define CIN  128
#define HH   56
#define WW   56
#define KOUT 256
#define HWS  (HH*WW)            // 3136
#define NHW  (NB*HWS)           // 100352
#define PADH 58                 // rows -1..56 -> 0..57 (0 and 57 zero pad)
#define XCNT ((float)(NB*CIN*HWS))
#define WCNT ((float)(KOUT*CIN*9))

// Zero sums + zero the 2 pad rows per image (3584 uint4). Grid 14 x 256.
__global__ __launch_bounds__(256) void init_kernel(uint4* __restrict__ xpad,
                                                   float* __restrict__ sums) {
    int idx = blockIdx.x * 256 + threadIdx.x;        // 0..3583
    if (idx < 2) sums[idx] = 0.0f;
    int n = idx / 112, rem = idx - n * 112;
    int prow = (rem < 56) ? 0 : 57;
    int w = rem % 56;
    xpad[(n * PADH + prow) * WW + w] = make_uint4(0, 0, 0, 0);
}

__device__ __forceinline__ void block_reduce_add(float v, float* dst) {
    #pragma unroll
    for (int off = 32; off > 0; off >>= 1) v += __shfl_down(v, off);
    __shared__ float ws4[4];
    int lane = threadIdx.x & 63, wid = threadIdx.x >> 6;
    if (lane == 0) ws4[wid] = v;
    __syncthreads();
    if (threadIdx.x == 0) {
        float s = ws4[0];
        int nw = (blockDim.x + 63) >> 6;
        for (int i = 1; i < nw; i++) s += ws4[i];
        atomicAdd(dst, s);
    }
}

// Thread per (spatial idx, 32-channel word j); writes into PADDED layout.
__global__ __launch_bounds__(256) void pack_x_kernel(const float* __restrict__ x,
                                                     uint32_t* __restrict__ xpadw,
                                                     float* __restrict__ sums) {
    int j   = blockIdx.x / (NHW / 256);              // 0..3, uniform per block
    int idx = (blockIdx.x - j * (NHW / 256)) * 256 + threadIdx.x;
    int n  = idx / HWS;
    int hw = idx - n * HWS;
    int h  = hw / WW;
    int w  = hw - h * WW;
    const float* p = x + (size_t)n * CIN * HWS + (size_t)(j * 32) * HWS + hw;
    float asum = 0.0f;
    uint32_t bits = 0;
    #pragma unroll
    for (int t = 0; t < 32; t++) {
        float v = p[(size_t)t * HWS];
        asum += fabsf(v);
        bits |= (v > 0.0f ? 1u : 0u) << t;
    }
    xpadw[(((n * PADH + h + 1) * WW + w) << 2) + j] = bits;
    block_reduce_add(asum, &sums[0]);
}

// Thread per (k, tap, word j): block = (tap, j) [36 blocks], lane = k (256).
__global__ __launch_bounds__(256) void pack_w_kernel(const float* __restrict__ wgt,
                                                     uint32_t* __restrict__ wpackTw,
                                                     float* __restrict__ sums) {
    int k   = threadIdx.x;
    int tap = blockIdx.x >> 2;
    int j   = blockIdx.x & 3;
    const float* p = wgt + (size_t)k * CIN * 9 + (size_t)(j * 32) * 9 + tap;
    float asum = 0.0f;
    uint32_t bits = 0;
    #pragma unroll
    for (int t = 0; t < 32; t++) {
        float v = p[(size_t)t * 9];
        asum += fabsf(v);
        bits |= (v > 0.0f ? 1u : 0u) << t;
    }
    wpackTw[(tap * KOUT + k) * 4 + j] = bits;
    block_reduce_add(asum, &sums[1]);
}

// Block = (n,h), 256 threads = 4 INDEPENDENT kg-waves (no barriers).
// COLUMN-MAJOR accumulation: input col c feeds 3 running output accumulators
// (out c-1 via dx=2 taps, out c via dx=1, out c+1 via dx=0). No multi-column
// register rotation — live set is current col + 1-col lookahead (2 q-sets),
// acc roles cycle mod 3, all indices compile-time (period-6 macro pattern).
// Pad rows are real zeros in xpad; pad cols algebraic (cs0/cs2 in F0/F55).
__global__ __launch_bounds__(256, 4) void conv_kernel(const uint4* __restrict__ xpad,
                                                      const uint4* __restrict__ wpackT,
                                                      const float* __restrict__ sums,
                                                      const float* __restrict__ bias,
                                                      float* __restrict__ out) {
    __shared__ float sbuf[256 * 10];

    int tid = threadIdx.x;
    int l   = tid & 63, kg = tid >> 6;
    int n   = blockIdx.x / HH, h = blockIdx.x - n * HH;

    uint4 wq[9];
    #pragma unroll
    for (int t = 0; t < 9; t++) wq[t] = wpackT[t * KOUT + tid];

    const uint4* R0 = xpad + (size_t)(n * PADH + h) * WW;   // padded rows h,h+1,h+2
    const uint4* R1 = R0 + WW;
    const uint4* R2 = R1 + WW;

    float scale = (sums[0] * (1.0f / XCNT)) * (sums[1] * (1.0f / WCNT));
    float m2s   = -2.0f * scale;
    float cbase = 1152.0f * scale + bias[tid];

    int pw[9];
    #pragma unroll
    for (int t = 0; t < 9; t++)
        pw[t] = __popc(wq[t].x) + __popc(wq[t].y) + __popc(wq[t].z) + __popc(wq[t].w);
    int cs0 = pw[0] + pw[3] + pw[6];
    int cs2 = pw[2] + pw[5] + pw[8];
    int rterm = 0, cc0 = 0, cc2 = 0;
    if (h == 0)        { rterm = 2*(pw[0]+pw[1]+pw[2]) - 384; cc0 = 128 - 2*pw[0]; cc2 = 128 - 2*pw[2]; }
    else if (h == HH-1){ rterm = 2*(pw[6]+pw[7]+pw[8]) - 384; cc0 = 128 - 2*pw[6]; cc2 = 128 - 2*pw[8]; }
    float KC  = cbase + scale * (float)rterm;                // interior const
    float F0  = KC + scale * (float)(2*cs0 - 384 + cc0);     // w = 0
    float F55 = KC + scale * (float)(2*cs2 - 384 + cc2);     // w = 55

    float* sb    = &sbuf[tid * 10];
    int    fbase = (kg * 64 + (l >> 2)) * 10 + (l & 3) * 2;
    float* o0 = out + ((size_t)(n * KOUT + kg * 64 + (l >> 2)) * HWS + h * WW + (l & 3) * 2);
    float* o1 = o0 + (size_t)16 * HWS;
    float* o2 = o1 + (size_t)16 * HWS;
    float* o3 = o2 + (size_t)16 * HWS;

#define T4(a, q, wt) a += __popc((q).x^(wt).x) + __popc((q).y^(wt).y) + __popc((q).z^(wt).z) + __popc((q).w^(wt).w);
#define FLUSH { \
    *(float2*)(o0) = *(float2*)&sbuf[fbase];       \
    *(float2*)(o1) = *(float2*)&sbuf[fbase + 160]; \
    *(float2*)(o2) = *(float2*)&sbuf[fbase + 320]; \
    *(float2*)(o3) = *(float2*)&sbuf[fbase + 480]; \
    o0 += 8; o1 += 8; o2 += 8; o3 += 8; }
// Consume (Q0,Q1,Q2) = col c; load col c+1 (P[CN]) into (N0,N1,N2);
// AM completes out[c-1] (emit to sb[SBI] with const K), AC = out[c], AP = out[c+1].
#define COLX(Q0,Q1,Q2, N0,N1,N2, AM,AC,AP, CN, SBI, K) { \
    N0 = P0[CN]; N1 = P1[CN]; N2 = P2[CN]; \
    T4(AM, Q0, wq[2]) T4(AM, Q1, wq[5]) T4(AM, Q2, wq[8]) \
    T4(AC, Q0, wq[1]) T4(AC, Q1, wq[4]) T4(AC, Q2, wq[7]) \
    T4(AP, Q0, wq[0]) T4(AP, Q1, wq[3]) T4(AP, Q2, wq[6]) \
    sb[SBI] = fmaf(m2s, (float)(AM), K); AM = 0; }
#define CA(AM,AC,AP, CN, SBI, K)  COLX(qa0,qa1,qa2, qb0,qb1,qb2, AM,AC,AP, CN, SBI, K)
#define CBX(AM,AC,AP, CN, SBI, K) COLX(qb0,qb1,qb2, qa0,qa1,qa2, AM,AC,AP, CN, SBI, K)

    int a0 = cs0, a1 = 0, a2 = 0;      // a0 = out0 (pretend col -1 = zeros; F0 corrects)
    uint4 qa0, qa1, qa2, qb0, qb1, qb2;

    // col 0: load it, then consume (no out[-1] part); lookahead col 1 -> B
    qa0 = R0[0]; qa1 = R1[0]; qa2 = R2[0];
    qb0 = R0[1]; qb1 = R1[1]; qb2 = R2[1];
    T4(a0, qa0, wq[1]) T4(a0, qa1, wq[4]) T4(a0, qa2, wq[7])
    T4(a1, qa0, wq[0]) T4(a1, qa1, wq[3]) T4(a1, qa2, wq[6])

    const uint4* P0 = R0 + 1;
    const uint4* P1 = R1 + 1;
    const uint4* P2 = R2 + 1;

    // cols 1..48 (emit w0..47), two 24-col groups; roles repeat with period 24
    #pragma unroll 1
    for (int i = 0; i < 2; i++) {
        float KF = (i == 0) ? F0 : KC;
        CBX(a0,a1,a2,  1, 0, KF) CA (a1,a2,a0,  2, 1, KC)
        CBX(a2,a0,a1,  3, 2, KC) CA (a0,a1,a2,  4, 3, KC)
        CBX(a1,a2,a0,  5, 4, KC) CA (a2,a0,a1,  6, 5, KC)
        CBX(a0,a1,a2,  7, 6, KC) CA (a1,a2,a0,  8, 7, KC)
        FLUSH
        CBX(a2,a0,a1,  9, 0, KC) CA (a0,a1,a2, 10, 1, KC)
        CBX(a1,a2,a0, 11, 2, KC) CA (a2,a0,a1, 12, 3, KC)
        CBX(a0,a1,a2, 13, 4, KC) CA (a1,a2,a0, 14, 5, KC)
        CBX(a2,a0,a1, 15, 6, KC) CA (a0,a1,a2, 16, 7, KC)
        FLUSH
        CBX(a1,a2,a0, 17, 0, KC) CA (a2,a0,a1, 18, 1, KC)
        CBX(a0,a1,a2, 19, 2, KC) CA (a1,a2,a0, 20, 3, KC)
        CBX(a2,a0,a1, 21, 4, KC) CA (a0,a1,a2, 22, 5, KC)
        CBX(a1,a2,a0, 23, 6, KC) CA (a2,a0,a1, 24, 7, KC)
        FLUSH
        P0 += 24; P1 += 24; P2 += 24;
    }

    // cols 49..54 (emit w48..53); P points at col 48
    CBX(a0,a1,a2, 1, 0, KC) CA (a1,a2,a0, 2, 1, KC)
    CBX(a2,a0,a1, 3, 2, KC) CA (a0,a1,a2, 4, 3, KC)
    CBX(a1,a2,a0, 5, 4, KC) CA (a2,a0,a1, 6, 5, KC)

    // col 55 (in B, no lookahead): emit w54; out55 completes with cs2 + F55
    T4(a0, qb0, wq[2]) T4(a0, qb1, wq[5]) T4(a0, qb2, wq[8])
    T4(a1, qb0, wq[1]) T4(a1, qb1, wq[4]) T4(a1, qb2, wq[7])
    sb[6] = fmaf(m2s, (float)a0, KC);
    sb[7] = fmaf(m2s, (float)(a1 + cs2), F55);
    FLUSH
}

extern "C" void kernel_launch(void* const* d_in, const int* in_sizes, int n_in,
                              void* d_out, int out_size, void* d_ws, size_t ws_size,
                              hipStream_t stream) {
    const float* x    = (const float*)d_in[0];
    const float* wgt  = (const float*)d_in[1];
    const float* bias = (const float*)d_in[2];
    float* out = (float*)d_out;

    // ws: sums (256B) | xpad 32*58*56 uint4 (1.59MB) | wpackT 2304 uint4 (36KB)
    float* sums   = (float*)d_ws;
    uint4* xpad   = (uint4*)((char*)d_ws + 256);
    uint4* wpackT = (uint4*)((char*)d_ws + 256 + (size_t)NB * PADH * WW * 16);

    hipLaunchKernelGGL(init_kernel, dim3(14), dim3(256), 0, stream, xpad, sums);
    hipLaunchKernelGGL(pack_w_kernel, dim3(36), dim3(256), 0, stream, wgt, (uint32_t*)wpackT, sums);
    hipLaunchKernelGGL(pack_x_kernel, dim3(4 * NHW / 256), dim3(256), 0, stream, x, (uint32_t*)xpad, sums);
    hipLaunchKernelGGL(conv_kernel, dim3(NB * HH), dim3(256), 0, stream, xpad, wpackT, sums, bias, out);
}